// Round 3
// baseline (495.513 us; speedup 1.0000x reference)
//
#include <hip/hip_runtime.h>

#define IMG_H 1024
#define IMG_W 1024
#define RPB   16      // output rows per block (R9: 8->16, halves prologue+halo overhead)
#define TPB   256     // each thread owns 4 columns
#define NBLK  ((IMG_H / RPB) * 32)   // 64 * 32 = 2048 = exactly 8 blocks/CU

struct HS { float x[4], y[4], xx[4], yy[4], xy[4]; };

__device__ __forceinline__ void zero_hs(HS& h)
{
#pragma unroll
    for (int j = 0; j < 4; ++j) { h.x[j]=0.f; h.y[j]=0.f; h.xx[j]=0.f; h.yy[j]=0.f; h.xy[j]=0.f; }
}

// Horizontal 3-sums from 6 inputs (halo scalars already masked by caller).
__device__ __forceinline__ void hsum6(float xl, float4 xv, float xr6,
                                      float yl, float4 yv, float yr6, HS& h)
{
    float xs[6] = { xl, xv.x, xv.y, xv.z, xv.w, xr6 };
    float ys[6] = { yl, yv.x, yv.y, yv.z, yv.w, yr6 };

    float pxx[6], pyy[6], pxy[6];
#pragma unroll
    for (int k = 0; k < 6; ++k) {
        pxx[k] = xs[k] * xs[k];
        pyy[k] = ys[k] * ys[k];
        pxy[k] = xs[k] * ys[k];
    }
#pragma unroll
    for (int j = 0; j < 4; ++j) {
        h.x[j]  = xs[j]  + xs[j + 1]  + xs[j + 2];
        h.y[j]  = ys[j]  + ys[j + 1]  + ys[j + 2];
        h.xx[j] = pxx[j] + pxx[j + 1] + pxx[j + 2];
        h.yy[j] = pyy[j] + pyy[j + 1] + pyy[j + 2];
        h.xy[j] = pxy[j] + pxy[j + 1] + pxy[j + 2];
    }
}

// Scaled SSIM (both num/den factors x81, EPS x6561; absmax==0 since R2):
//   num = (2*sx*sy + 81*C1) * (18*sxy - 2*sx*sy + 81*C2)
//   den = (sx^2+sy^2 + 81*C1) * (9*(sxx+syy) - (sx^2+sy^2) + 81*C2) + 6561*EPS
__device__ __forceinline__ void accum(const HS& A, const HS& B, const HS& C, float& acc)
{
    const float c1s  = 81.0f * 1e-4f;
    const float c2s  = 81.0f * 9e-4f;
    const float epss = 6561.0f * 1e-8f;
#pragma unroll
    for (int j = 0; j < 4; ++j) {
        const float sx  = A.x[j]  + B.x[j]  + C.x[j];
        const float sy  = A.y[j]  + B.y[j]  + C.y[j];
        const float sxx = A.xx[j] + B.xx[j] + C.xx[j];
        const float syy = A.yy[j] + B.yy[j] + C.yy[j];
        const float sxy = A.xy[j] + B.xy[j] + C.xy[j];

        const float t1 = sx * sy;
        const float t2 = fmaf(sx, sx, sy * sy);
        const float s2 = sxx + syy;
        const float An = fmaf(2.0f, t1, c1s);
        const float Bn = fmaf(-2.0f, t1, fmaf(18.0f, sxy, c2s));
        const float Xd = t2 + c1s;
        const float Yd = fmaf(9.0f, s2, c2s - t2);
        const float den = fmaf(Xd, Yd, epss);
        const float num = An * Bn;
        acc = fmaf(num, __builtin_amdgcn_rcpf(den), acc);
    }
}

// R9: R8 compute, three structural changes (R8's halo-hoist was NULL — compiler
// had already scheduled it; VGPR/dur/fetch identical):
//  1. RPB 8->16: prologue rows 2/18 instead of 2/10 (read amp 1.25->1.125),
//     half the per-CU prologue latency chains.
//  2. Grid = 2048 blocks = EXACTLY 8 blocks/CU; __launch_bounds__(256,8) caps
//     VGPR at 64 so all 32 waves/CU are co-resident -> whole dispatch runs in
//     one round, no inter-round ramp/drain.
//  3. Bijective XCD swizzle (2048%8==0): each XCD owns contiguous row-block
//     spans, so the 2 shared halo rows between adjacent blocks hit the local
//     L2 instead of crossing XCDs to L3.
__global__ __launch_bounds__(TPB, 8)
void ssim_map_sum_kernel(const float* __restrict__ x,
                         const float* __restrict__ y,
                         float* __restrict__ part)
{
    // XCD-aware bijective swizzle: orig%8 = XCD; give each XCD a contiguous
    // 256-block chunk of (image, row-block) space.
    const int orig = (int)blockIdx.x;
    const int wgid = (orig & 7) * (NBLK / 8) + (orig >> 3);
    const int rb = wgid % (IMG_H / RPB);
    const int n  = wgid / (IMG_H / RPB);
    const int r0 = rb * RPB;
    const int c  = (int)threadIdx.x * 4;

    const int   cl = (c > 0) ? c - 1 : 0;
    const int   cr = (c + 4 < IMG_W) ? c + 4 : IMG_W - 1;
    const float lm = (c > 0) ? 1.0f : 0.0f;
    const float rm = (c + 4 < IMG_W) ? 1.0f : 0.0f;

    const float* xi = x + (size_t)n * IMG_H * IMG_W;
    const float* yi = y + (size_t)n * IMG_H * IMG_W;

    HS hA, hB, hC;

    // ---- Prologue: hA = row r0-1 (or zero), hB = row r0.
    if (r0 > 0) {
        const float* xr = xi + (size_t)(r0 - 1) * IMG_W;
        const float* yr = yi + (size_t)(r0 - 1) * IMG_W;
        hsum6(xr[cl] * lm, *reinterpret_cast<const float4*>(xr + c), xr[cr] * rm,
              yr[cl] * lm, *reinterpret_cast<const float4*>(yr + c), yr[cr] * rm, hA);
    } else {
        zero_hs(hA);
    }
    {
        const float* xr = xi + (size_t)r0 * IMG_W;
        const float* yr = yi + (size_t)r0 * IMG_W;
        hsum6(xr[cl] * lm, *reinterpret_cast<const float4*>(xr + c), xr[cr] * rm,
              yr[cl] * lm, *reinterpret_cast<const float4*>(yr + c), yr[cr] * rm, hB);
    }

    // Prefetch row r0+1 (always in-bounds): float4s AND the 4 halo scalars,
    // double-buffered in named registers (a/b).
    float4 pxa, pya, pxb, pyb;
    float  xla, xra, yla, yra, xlb, xrb, ylb, yrb;
    {
        const float* xr = xi + (size_t)(r0 + 1) * IMG_W;
        const float* yr = yi + (size_t)(r0 + 1) * IMG_W;
        pxa = *reinterpret_cast<const float4*>(xr + c);
        pya = *reinterpret_cast<const float4*>(yr + c);
        xla = xr[cl]; xra = xr[cr];
        yla = yr[cl]; yra = yr[cr];
    }

    float acc = 0.0f;

    // Step k (output row r0+k): FIRST issue ALL loads of row r0+k+2 into the
    // other buffer — a full step of slack before their wait — THEN consume the
    // fully-buffered row r0+k+1 from registers only.
#define STEP_MAIN(k, PXI, PYI, XLI, XRI, YLI, YRI, PXO, PYO, XLO, XRO, YLO, YRO, P, Q, R) \
    {                                                                              \
        const float* xw = xi + (size_t)(r0 + (k) + 2) * IMG_W;                     \
        const float* yw = yi + (size_t)(r0 + (k) + 2) * IMG_W;                     \
        PXO = *reinterpret_cast<const float4*>(xw + c);                            \
        PYO = *reinterpret_cast<const float4*>(yw + c);                            \
        XLO = xw[cl]; XRO = xw[cr];                                                \
        YLO = yw[cl]; YRO = yw[cr];                                                \
        hsum6(XLI * lm, PXI, XRI * rm, YLI * lm, PYI, YRI * rm, R);                \
        accum(P, Q, R, acc);                                                       \
    }
#define STEP_A2B(k, P, Q, R) STEP_MAIN(k, pxa, pya, xla, xra, yla, yra, pxb, pyb, xlb, xrb, ylb, yrb, P, Q, R)
#define STEP_B2A(k, P, Q, R) STEP_MAIN(k, pxb, pyb, xlb, xrb, ylb, yrb, pxa, pya, xla, xra, yla, yra, P, Q, R)

    // k = 0..13: prefetched rows r0+2 .. r0+15 all in-bounds (r0 <= IMG_H-RPB).
    STEP_A2B(0,  hA, hB, hC)
    STEP_B2A(1,  hB, hC, hA)
    STEP_A2B(2,  hC, hA, hB)
    STEP_B2A(3,  hA, hB, hC)
    STEP_A2B(4,  hB, hC, hA)
    STEP_B2A(5,  hC, hA, hB)
    STEP_A2B(6,  hA, hB, hC)
    STEP_B2A(7,  hB, hC, hA)
    STEP_A2B(8,  hC, hA, hB)
    STEP_B2A(9,  hA, hB, hC)
    STEP_A2B(10, hB, hC, hA)
    STEP_B2A(11, hC, hA, hB)
    STEP_A2B(12, hA, hB, hC)
    STEP_B2A(13, hB, hC, hA)
#undef STEP_A2B
#undef STEP_B2A
#undef STEP_MAIN

    // k = 14: prefetch row r0+16 with CLAMPED row index (OOB only for the last
    // block-row; masked at consume). Consume prefetched row r0+15 normally.
    {
        const int rr = (r0 + RPB < IMG_H) ? r0 + RPB : IMG_H - 1;
        const float* xw = xi + (size_t)rr * IMG_W;
        const float* yw = yi + (size_t)rr * IMG_W;
        pxb = *reinterpret_cast<const float4*>(xw + c);
        pyb = *reinterpret_cast<const float4*>(yw + c);
        xlb = xw[cl]; xrb = xw[cr];
        ylb = yw[cl]; yrb = yw[cr];
        hsum6(xla * lm, pxa, xra * rm, yla * lm, pya, yra * rm, hB);
        accum(hC, hA, hB, acc);              // output row r0+14
    }

    // k = 15 (final output row r0+15): consume row r0+16, row-masked (rwm=0
    // zeroes the whole row's contribution for the last block-row; loads were
    // clamped so no OOB reads).
    {
        const float rwm = (r0 + RPB < IMG_H) ? 1.0f : 0.0f;
        float4 xv = pxb, yv = pyb;
        xv.x *= rwm; xv.y *= rwm; xv.z *= rwm; xv.w *= rwm;
        yv.x *= rwm; yv.y *= rwm; yv.z *= rwm; yv.w *= rwm;
        hsum6(xlb * (lm * rwm), xv, xrb * (rm * rwm),
              ylb * (lm * rwm), yv, yrb * (rm * rwm), hC);
        accum(hA, hB, hC, acc);
    }

    // ---- Reduction: wave shuffle -> LDS -> ONE STORE per block.
#pragma unroll
    for (int off = 32; off > 0; off >>= 1)
        acc += __shfl_down(acc, off);

    __shared__ float red[TPB / 64];
    const int lane = (int)threadIdx.x & 63;
    const int wave = (int)threadIdx.x >> 6;
    if (lane == 0) red[wave] = acc;
    __syncthreads();
    if (threadIdx.x == 0) {
        float s = 0.0f;
#pragma unroll
        for (int w = 0; w < TPB / 64; ++w) s += red[w];
        part[blockIdx.x] = s;
    }
}

__global__ __launch_bounds__(256)
void ssim_finalize_kernel(const float* __restrict__ part, int nparts,
                          float* __restrict__ out, float inv_count)
{
    float s = 0.0f;
    for (int i = (int)threadIdx.x; i < nparts; i += 256)
        s += part[i];
#pragma unroll
    for (int off = 32; off > 0; off >>= 1)
        s += __shfl_down(s, off);

    __shared__ float red[4];
    const int lane = (int)threadIdx.x & 63;
    const int wave = (int)threadIdx.x >> 6;
    if (lane == 0) red[wave] = s;
    __syncthreads();
    if (threadIdx.x == 0) {
        float t = red[0] + red[1] + red[2] + red[3];
        out[0] = 1.0f - t * inv_count;
    }
}

extern "C" void kernel_launch(void* const* d_in, const int* in_sizes, int n_in,
                              void* d_out, int out_size, void* d_ws, size_t ws_size,
                              hipStream_t stream)
{
    const float* x = (const float*)d_in[0];
    const float* y = (const float*)d_in[1];
    float* out  = (float*)d_out;
    float* part = (float*)d_ws;   // 2048 floats = 8 KB << ws_size

    const long long total = (long long)in_sizes[0];       // 32*1024*1024
    const int N = (int)(total / ((long long)IMG_H * IMG_W));
    const int nparts = (IMG_H / RPB) * N;

    ssim_map_sum_kernel<<<dim3(nparts), TPB, 0, stream>>>(x, y, part);

    ssim_finalize_kernel<<<1, 256, 0, stream>>>(part, nparts, out, 1.0f / (float)total);
}

// Round 4
// 288.487 us; speedup vs baseline: 1.7176x; 1.7176x over previous
//
#include <hip/hip_runtime.h>

#define IMG_H 1024
#define IMG_W 1024
#define RPB   16      // output rows per block (halves prologue + halo overhead vs 8)
#define TPB   256     // each thread owns 4 columns
#define NBLK  ((IMG_H / RPB) * 32)   // 64 * 32 = 2048 blocks = 8 blocks/CU

struct HS { float x[4], y[4], xx[4], yy[4], xy[4]; };

__device__ __forceinline__ void zero_hs(HS& h)
{
#pragma unroll
    for (int j = 0; j < 4; ++j) { h.x[j]=0.f; h.y[j]=0.f; h.xx[j]=0.f; h.yy[j]=0.f; h.xy[j]=0.f; }
}

// Horizontal 3-sums from 6 inputs (halo scalars already masked by caller).
__device__ __forceinline__ void hsum6(float xl, float4 xv, float xr6,
                                      float yl, float4 yv, float yr6, HS& h)
{
    float xs[6] = { xl, xv.x, xv.y, xv.z, xv.w, xr6 };
    float ys[6] = { yl, yv.x, yv.y, yv.z, yv.w, yr6 };

    float pxx[6], pyy[6], pxy[6];
#pragma unroll
    for (int k = 0; k < 6; ++k) {
        pxx[k] = xs[k] * xs[k];
        pyy[k] = ys[k] * ys[k];
        pxy[k] = xs[k] * ys[k];
    }
#pragma unroll
    for (int j = 0; j < 4; ++j) {
        h.x[j]  = xs[j]  + xs[j + 1]  + xs[j + 2];
        h.y[j]  = ys[j]  + ys[j + 1]  + ys[j + 2];
        h.xx[j] = pxx[j] + pxx[j + 1] + pxx[j + 2];
        h.yy[j] = pyy[j] + pyy[j + 1] + pyy[j + 2];
        h.xy[j] = pxy[j] + pxy[j + 1] + pxy[j + 2];
    }
}

// Scaled SSIM (both num/den factors x81, EPS x6561; absmax==0 since R2):
//   num = (2*sx*sy + 81*C1) * (18*sxy - 2*sx*sy + 81*C2)
//   den = (sx^2+sy^2 + 81*C1) * (9*(sxx+syy) - (sx^2+sy^2) + 81*C2) + 6561*EPS
__device__ __forceinline__ void accum(const HS& A, const HS& B, const HS& C, float& acc)
{
    const float c1s  = 81.0f * 1e-4f;
    const float c2s  = 81.0f * 9e-4f;
    const float epss = 6561.0f * 1e-8f;
#pragma unroll
    for (int j = 0; j < 4; ++j) {
        const float sx  = A.x[j]  + B.x[j]  + C.x[j];
        const float sy  = A.y[j]  + B.y[j]  + C.y[j];
        const float sxx = A.xx[j] + B.xx[j] + C.xx[j];
        const float syy = A.yy[j] + B.yy[j] + C.yy[j];
        const float sxy = A.xy[j] + B.xy[j] + C.xy[j];

        const float t1 = sx * sy;
        const float t2 = fmaf(sx, sx, sy * sy);
        const float s2 = sxx + syy;
        const float An = fmaf(2.0f, t1, c1s);
        const float Bn = fmaf(-2.0f, t1, fmaf(18.0f, sxy, c2s));
        const float Xd = t2 + c1s;
        const float Yd = fmaf(9.0f, s2, c2s - t2);
        const float den = fmaf(Xd, Yd, epss);
        const float num = An * Bn;
        acc = fmaf(num, __builtin_amdgcn_rcpf(den), acc);
    }
}

// R10 = R9 with the spill fixed. R9's __launch_bounds__(256,8) capped VGPR at
// 32 (< ~60 live floats) -> 1.18 GB scratch traffic, 315us. Occupancy rose to
// 88% while perf fell 3x — occupancy was never the binding constraint; the
// register budget is. Keep (256,4): 56-72 VGPR, no spill, still allows 8
// blocks/CU by register count. RPB=16 + bijective XCD swizzle retained
// (untested in R9 — masked by the spill).
__global__ __launch_bounds__(TPB, 4)
void ssim_map_sum_kernel(const float* __restrict__ x,
                         const float* __restrict__ y,
                         float* __restrict__ part)
{
    // XCD-aware bijective swizzle: orig%8 = XCD; give each XCD a contiguous
    // 256-block chunk of (image, row-block) space so adjacent row-blocks
    // (sharing 2 halo rows) land on the same XCD's L2.
    const int orig = (int)blockIdx.x;
    const int wgid = (orig & 7) * (NBLK / 8) + (orig >> 3);
    const int rb = wgid % (IMG_H / RPB);
    const int n  = wgid / (IMG_H / RPB);
    const int r0 = rb * RPB;
    const int c  = (int)threadIdx.x * 4;

    const int   cl = (c > 0) ? c - 1 : 0;
    const int   cr = (c + 4 < IMG_W) ? c + 4 : IMG_W - 1;
    const float lm = (c > 0) ? 1.0f : 0.0f;
    const float rm = (c + 4 < IMG_W) ? 1.0f : 0.0f;

    const float* xi = x + (size_t)n * IMG_H * IMG_W;
    const float* yi = y + (size_t)n * IMG_H * IMG_W;

    HS hA, hB, hC;

    // ---- Prologue: hA = row r0-1 (or zero), hB = row r0.
    if (r0 > 0) {
        const float* xr = xi + (size_t)(r0 - 1) * IMG_W;
        const float* yr = yi + (size_t)(r0 - 1) * IMG_W;
        hsum6(xr[cl] * lm, *reinterpret_cast<const float4*>(xr + c), xr[cr] * rm,
              yr[cl] * lm, *reinterpret_cast<const float4*>(yr + c), yr[cr] * rm, hA);
    } else {
        zero_hs(hA);
    }
    {
        const float* xr = xi + (size_t)r0 * IMG_W;
        const float* yr = yi + (size_t)r0 * IMG_W;
        hsum6(xr[cl] * lm, *reinterpret_cast<const float4*>(xr + c), xr[cr] * rm,
              yr[cl] * lm, *reinterpret_cast<const float4*>(yr + c), yr[cr] * rm, hB);
    }

    // Prefetch row r0+1 (always in-bounds): float4s AND the 4 halo scalars,
    // double-buffered in named registers (a/b).
    float4 pxa, pya, pxb, pyb;
    float  xla, xra, yla, yra, xlb, xrb, ylb, yrb;
    {
        const float* xr = xi + (size_t)(r0 + 1) * IMG_W;
        const float* yr = yi + (size_t)(r0 + 1) * IMG_W;
        pxa = *reinterpret_cast<const float4*>(xr + c);
        pya = *reinterpret_cast<const float4*>(yr + c);
        xla = xr[cl]; xra = xr[cr];
        yla = yr[cl]; yra = yr[cr];
    }

    float acc = 0.0f;

    // Step k (output row r0+k): FIRST issue ALL loads of row r0+k+2 into the
    // other buffer — a full step of slack before their wait — THEN consume the
    // fully-buffered row r0+k+1 from registers only.
#define STEP_MAIN(k, PXI, PYI, XLI, XRI, YLI, YRI, PXO, PYO, XLO, XRO, YLO, YRO, P, Q, R) \
    {                                                                              \
        const float* xw = xi + (size_t)(r0 + (k) + 2) * IMG_W;                     \
        const float* yw = yi + (size_t)(r0 + (k) + 2) * IMG_W;                     \
        PXO = *reinterpret_cast<const float4*>(xw + c);                            \
        PYO = *reinterpret_cast<const float4*>(yw + c);                            \
        XLO = xw[cl]; XRO = xw[cr];                                                \
        YLO = yw[cl]; YRO = yw[cr];                                                \
        hsum6(XLI * lm, PXI, XRI * rm, YLI * lm, PYI, YRI * rm, R);                \
        accum(P, Q, R, acc);                                                       \
    }
#define STEP_A2B(k, P, Q, R) STEP_MAIN(k, pxa, pya, xla, xra, yla, yra, pxb, pyb, xlb, xrb, ylb, yrb, P, Q, R)
#define STEP_B2A(k, P, Q, R) STEP_MAIN(k, pxb, pyb, xlb, xrb, ylb, yrb, pxa, pya, xla, xra, yla, yra, P, Q, R)

    // k = 0..13: prefetched rows r0+2 .. r0+15 all in-bounds (r0 <= IMG_H-RPB).
    STEP_A2B(0,  hA, hB, hC)
    STEP_B2A(1,  hB, hC, hA)
    STEP_A2B(2,  hC, hA, hB)
    STEP_B2A(3,  hA, hB, hC)
    STEP_A2B(4,  hB, hC, hA)
    STEP_B2A(5,  hC, hA, hB)
    STEP_A2B(6,  hA, hB, hC)
    STEP_B2A(7,  hB, hC, hA)
    STEP_A2B(8,  hC, hA, hB)
    STEP_B2A(9,  hA, hB, hC)
    STEP_A2B(10, hB, hC, hA)
    STEP_B2A(11, hC, hA, hB)
    STEP_A2B(12, hA, hB, hC)
    STEP_B2A(13, hB, hC, hA)
#undef STEP_A2B
#undef STEP_B2A
#undef STEP_MAIN

    // k = 14: prefetch row r0+16 with CLAMPED row index (OOB only for the last
    // block-row; masked at consume). Consume prefetched row r0+15 normally.
    {
        const int rr = (r0 + RPB < IMG_H) ? r0 + RPB : IMG_H - 1;
        const float* xw = xi + (size_t)rr * IMG_W;
        const float* yw = yi + (size_t)rr * IMG_W;
        pxb = *reinterpret_cast<const float4*>(xw + c);
        pyb = *reinterpret_cast<const float4*>(yw + c);
        xlb = xw[cl]; xrb = xw[cr];
        ylb = yw[cl]; yrb = yw[cr];
        hsum6(xla * lm, pxa, xra * rm, yla * lm, pya, yra * rm, hB);
        accum(hC, hA, hB, acc);              // output row r0+14
    }

    // k = 15 (final output row r0+15): consume row r0+16, row-masked (rwm=0
    // zeroes the whole row's contribution for the last block-row; loads were
    // clamped so no OOB reads).
    {
        const float rwm = (r0 + RPB < IMG_H) ? 1.0f : 0.0f;
        float4 xv = pxb, yv = pyb;
        xv.x *= rwm; xv.y *= rwm; xv.z *= rwm; xv.w *= rwm;
        yv.x *= rwm; yv.y *= rwm; yv.z *= rwm; yv.w *= rwm;
        hsum6(xlb * (lm * rwm), xv, xrb * (rm * rwm),
              ylb * (lm * rwm), yv, yrb * (rm * rwm), hC);
        accum(hA, hB, hC, acc);
    }

    // ---- Reduction: wave shuffle -> LDS -> ONE STORE per block.
#pragma unroll
    for (int off = 32; off > 0; off >>= 1)
        acc += __shfl_down(acc, off);

    __shared__ float red[TPB / 64];
    const int lane = (int)threadIdx.x & 63;
    const int wave = (int)threadIdx.x >> 6;
    if (lane == 0) red[wave] = acc;
    __syncthreads();
    if (threadIdx.x == 0) {
        float s = 0.0f;
#pragma unroll
        for (int w = 0; w < TPB / 64; ++w) s += red[w];
        part[blockIdx.x] = s;
    }
}

__global__ __launch_bounds__(256)
void ssim_finalize_kernel(const float* __restrict__ part, int nparts,
                          float* __restrict__ out, float inv_count)
{
    float s = 0.0f;
    for (int i = (int)threadIdx.x; i < nparts; i += 256)
        s += part[i];
#pragma unroll
    for (int off = 32; off > 0; off >>= 1)
        s += __shfl_down(s, off);

    __shared__ float red[4];
    const int lane = (int)threadIdx.x & 63;
    const int wave = (int)threadIdx.x >> 6;
    if (lane == 0) red[wave] = s;
    __syncthreads();
    if (threadIdx.x == 0) {
        float t = red[0] + red[1] + red[2] + red[3];
        out[0] = 1.0f - t * inv_count;
    }
}

extern "C" void kernel_launch(void* const* d_in, const int* in_sizes, int n_in,
                              void* d_out, int out_size, void* d_ws, size_t ws_size,
                              hipStream_t stream)
{
    const float* x = (const float*)d_in[0];
    const float* y = (const float*)d_in[1];
    float* out  = (float*)d_out;
    float* part = (float*)d_ws;   // 2048 floats = 8 KB << ws_size

    const long long total = (long long)in_sizes[0];       // 32*1024*1024
    const int N = (int)(total / ((long long)IMG_H * IMG_W));
    const int nparts = (IMG_H / RPB) * N;

    ssim_map_sum_kernel<<<dim3(nparts), TPB, 0, stream>>>(x, y, part);

    ssim_finalize_kernel<<<1, 256, 0, stream>>>(part, nparts, out, 1.0f / (float)total);
}

// Round 6
// 283.897 us; speedup vs baseline: 1.7454x; 1.0162x over previous
//
#include <hip/hip_runtime.h>

#define IMG_H 1024
#define IMG_W 1024
#define RPB   8       // output rows per block (R8 base — best measured structure)
#define TPB   256     // each thread owns 4 columns

struct HS { float x[4], y[4], xx[4], yy[4], xy[4]; };

__device__ __forceinline__ void zero_hs(HS& h)
{
#pragma unroll
    for (int j = 0; j < 4; ++j) { h.x[j]=0.f; h.y[j]=0.f; h.xx[j]=0.f; h.yy[j]=0.f; h.xy[j]=0.f; }
}

// Horizontal 3-sums from 6 inputs (halo scalars already masked by caller).
__device__ __forceinline__ void hsum6(float xl, float4 xv, float xr6,
                                      float yl, float4 yv, float yr6, HS& h)
{
    float xs[6] = { xl, xv.x, xv.y, xv.z, xv.w, xr6 };
    float ys[6] = { yl, yv.x, yv.y, yv.z, yv.w, yr6 };

    float pxx[6], pyy[6], pxy[6];
#pragma unroll
    for (int k = 0; k < 6; ++k) {
        pxx[k] = xs[k] * xs[k];
        pyy[k] = ys[k] * ys[k];
        pxy[k] = xs[k] * ys[k];
    }
#pragma unroll
    for (int j = 0; j < 4; ++j) {
        h.x[j]  = xs[j]  + xs[j + 1]  + xs[j + 2];
        h.y[j]  = ys[j]  + ys[j + 1]  + ys[j + 2];
        h.xx[j] = pxx[j] + pxx[j + 1] + pxx[j + 2];
        h.yy[j] = pyy[j] + pyy[j + 1] + pyy[j + 2];
        h.xy[j] = pxy[j] + pxy[j + 1] + pxy[j + 2];
    }
}

// Scaled SSIM (both num/den factors x81, EPS x6561; absmax==0 since R2):
//   num = (2*sx*sy + 81*C1) * (18*sxy - 2*sx*sy + 81*C2)
//   den = (sx^2+sy^2 + 81*C1) * (9*(sxx+syy) - (sx^2+sy^2) + 81*C2) + 6561*EPS
__device__ __forceinline__ void accum(const HS& A, const HS& B, const HS& C, float& acc)
{
    const float c1s  = 81.0f * 1e-4f;
    const float c2s  = 81.0f * 9e-4f;
    const float epss = 6561.0f * 1e-8f;
#pragma unroll
    for (int j = 0; j < 4; ++j) {
        const float sx  = A.x[j]  + B.x[j]  + C.x[j];
        const float sy  = A.y[j]  + B.y[j]  + C.y[j];
        const float sxx = A.xx[j] + B.xx[j] + C.xx[j];
        const float syy = A.yy[j] + B.yy[j] + C.yy[j];
        const float sxy = A.xy[j] + B.xy[j] + C.xy[j];

        const float t1 = sx * sy;
        const float t2 = fmaf(sx, sx, sy * sy);
        const float s2 = sxx + syy;
        const float An = fmaf(2.0f, t1, c1s);
        const float Bn = fmaf(-2.0f, t1, fmaf(18.0f, sxy, c2s));
        const float Xd = t2 + c1s;
        const float Yd = fmaf(9.0f, s2, c2s - t2);
        const float den = fmaf(Xd, Yd, epss);
        const float num = An * Bn;
        acc = fmaf(num, __builtin_amdgcn_rcpf(den), acc);
    }
}

// R11 = R8 base (RPB=8, 4096 blocks, 2D grid — best measured at 102us) with
// prefetch depth 2 via TRIPLE buffering. Evidence: R6/R8/R10 all show ~65-70%
// SIMD idle with HBM at 20-25% — every wave stalls at s_waitcnt each step
// because a row's loads get only ~1 step (~400cy) of slack vs a loaded-system
// latency that's clearly larger (R9's spill kernel sustained 3.75 TB/s purely
// by having more requests in flight). Depth 2 doubles both the slack (2 steps)
// and the in-flight bytes per wave (12 loads, ~4.5KB). Same loads, same
// summation order -> absmax 0. Watch: VGPR must stay <~80, WRITE_SIZE <1MB
// (else the extra buffer spilled — the R7/R9 failure mode).
__global__ __launch_bounds__(TPB, 4)
void ssim_map_sum_kernel(const float* __restrict__ x,
                         const float* __restrict__ y,
                         float* __restrict__ part)
{
    const int rb = blockIdx.x;
    const int n  = blockIdx.y;
    const int r0 = rb * RPB;
    const int c  = (int)threadIdx.x * 4;

    const int   cl = (c > 0) ? c - 1 : 0;
    const int   cr = (c + 4 < IMG_W) ? c + 4 : IMG_W - 1;
    const float lm = (c > 0) ? 1.0f : 0.0f;
    const float rm = (c + 4 < IMG_W) ? 1.0f : 0.0f;

    const float* xi = x + (size_t)n * IMG_H * IMG_W;
    const float* yi = y + (size_t)n * IMG_H * IMG_W;

    HS hA, hB, hC;

    // ---- Prologue: hA = row r0-1 (or zero), hB = row r0 (direct loads).
    if (r0 > 0) {
        const float* xr = xi + (size_t)(r0 - 1) * IMG_W;
        const float* yr = yi + (size_t)(r0 - 1) * IMG_W;
        hsum6(xr[cl] * lm, *reinterpret_cast<const float4*>(xr + c), xr[cr] * rm,
              yr[cl] * lm, *reinterpret_cast<const float4*>(yr + c), yr[cr] * rm, hA);
    } else {
        zero_hs(hA);
    }
    {
        const float* xr = xi + (size_t)r0 * IMG_W;
        const float* yr = yi + (size_t)r0 * IMG_W;
        hsum6(xr[cl] * lm, *reinterpret_cast<const float4*>(xr + c), xr[cr] * rm,
              yr[cl] * lm, *reinterpret_cast<const float4*>(yr + c), yr[cr] * rm, hB);
    }

    // Triple prefetch buffers (12 floats each): float4 x/y + 4 halo scalars.
    float4 pxA, pyA, pxB, pyB, pxC, pyC;
    float  xlA, xrA, ylA, yrA, xlB, xrB, ylB, yrB, xlC, xrC, ylC, yrC;

#define LOADBUF(row, S)                                                        \
    {                                                                          \
        const float* xr_ = xi + (size_t)(row) * IMG_W;                         \
        const float* yr_ = yi + (size_t)(row) * IMG_W;                         \
        px##S = *reinterpret_cast<const float4*>(xr_ + c);                     \
        py##S = *reinterpret_cast<const float4*>(yr_ + c);                     \
        xl##S = xr_[cl]; xr##S = xr_[cr];                                      \
        yl##S = yr_[cl]; yr##S = yr_[cr];                                      \
    }

    // Prologue prefetch: rows r0+1, r0+2 (always in-bounds: r0 <= 1016).
    LOADBUF(r0 + 1, A)
    LOADBUF(r0 + 2, B)

    float acc = 0.0f;

    // Consume buffer S (row loaded 2 steps ago) into HS slot H.
#define CONSUME(S, H)                                                          \
    hsum6(xl##S * lm, px##S, xr##S * rm, yl##S * lm, py##S, yr##S * rm, H);

    // Steps k=0..5: issue row r0+k+3 (2 steps ahead), consume row r0+k+1.
    // Rows r0+3..r0+7 always in-bounds; r0+8 clamped (masked at consume).
    /* k=0 */ LOADBUF(r0 + 3, C) CONSUME(A, hC) accum(hA, hB, hC, acc);
    /* k=1 */ LOADBUF(r0 + 4, A) CONSUME(B, hA) accum(hB, hC, hA, acc);
    /* k=2 */ LOADBUF(r0 + 5, B) CONSUME(C, hB) accum(hC, hA, hB, acc);
    /* k=3 */ LOADBUF(r0 + 6, C) CONSUME(A, hC) accum(hA, hB, hC, acc);
    /* k=4 */ LOADBUF(r0 + 7, A) CONSUME(B, hA) accum(hB, hC, hA, acc);
    /* k=5 */ {
        const int rr = (r0 + 8 < IMG_H) ? r0 + 8 : IMG_H - 1;
        LOADBUF(rr, B)
        CONSUME(C, hB) accum(hC, hA, hB, acc);
    }
    /* k=6 */ CONSUME(A, hC) accum(hA, hB, hC, acc);   // row r0+7 (in-bounds)
    /* k=7: consume row r0+8, row-masked (rwm=0 zeroes the whole row for the
       last block-row; its loads were clamped so no OOB reads). */
    {
        const float rwm = (r0 + 8 < IMG_H) ? 1.0f : 0.0f;
        float4 xv = pxB, yv = pyB;
        xv.x *= rwm; xv.y *= rwm; xv.z *= rwm; xv.w *= rwm;
        yv.x *= rwm; yv.y *= rwm; yv.z *= rwm; yv.w *= rwm;
        hsum6(xlB * (lm * rwm), xv, xrB * (rm * rwm),
              ylB * (lm * rwm), yv, yrB * (rm * rwm), hA);
        accum(hB, hC, hA, acc);
    }
#undef CONSUME
#undef LOADBUF

    // ---- Reduction: wave shuffle -> LDS -> ONE STORE per block.
#pragma unroll
    for (int off = 32; off > 0; off >>= 1)
        acc += __shfl_down(acc, off);

    __shared__ float red[TPB / 64];
    const int lane = (int)threadIdx.x & 63;
    const int wave = (int)threadIdx.x >> 6;
    if (lane == 0) red[wave] = acc;
    __syncthreads();
    if (threadIdx.x == 0) {
        float s = 0.0f;
#pragma unroll
        for (int w = 0; w < TPB / 64; ++w) s += red[w];
        part[blockIdx.y * gridDim.x + blockIdx.x] = s;
    }
}

__global__ __launch_bounds__(256)
void ssim_finalize_kernel(const float* __restrict__ part, int nparts,
                          float* __restrict__ out, float inv_count)
{
    float s = 0.0f;
    for (int i = (int)threadIdx.x; i < nparts; i += 256)
        s += part[i];
#pragma unroll
    for (int off = 32; off > 0; off >>= 1)
        s += __shfl_down(s, off);

    __shared__ float red[4];
    const int lane = (int)threadIdx.x & 63;
    const int wave = (int)threadIdx.x >> 6;
    if (lane == 0) red[wave] = s;
    __syncthreads();
    if (threadIdx.x == 0) {
        float t = red[0] + red[1] + red[2] + red[3];
        out[0] = 1.0f - t * inv_count;
    }
}

extern "C" void kernel_launch(void* const* d_in, const int* in_sizes, int n_in,
                              void* d_out, int out_size, void* d_ws, size_t ws_size,
                              hipStream_t stream)
{
    const float* x = (const float*)d_in[0];
    const float* y = (const float*)d_in[1];
    float* out  = (float*)d_out;
    float* part = (float*)d_ws;   // 4096 floats = 16 KB << ws_size

    const long long total = (long long)in_sizes[0];       // 32*1024*1024
    const int N = (int)(total / ((long long)IMG_H * IMG_W));
    const int nparts = (IMG_H / RPB) * N;

    dim3 grid(IMG_H / RPB, N);
    ssim_map_sum_kernel<<<grid, TPB, 0, stream>>>(x, y, part);

    ssim_finalize_kernel<<<1, 256, 0, stream>>>(part, nparts, out, 1.0f / (float)total);
}

// Round 7
// 283.438 us; speedup vs baseline: 1.7482x; 1.0016x over previous
//
#include <hip/hip_runtime.h>

#define IMG_H 1024
#define IMG_W 1024
#define RPB   8       // output rows per block
#define TPB   256     // each thread owns 4 columns

struct HS { float x[4], y[4], xx[4], yy[4], xy[4]; };

__device__ __forceinline__ void zero_hs(HS& h)
{
#pragma unroll
    for (int j = 0; j < 4; ++j) { h.x[j]=0.f; h.y[j]=0.f; h.xx[j]=0.f; h.yy[j]=0.f; h.xy[j]=0.f; }
}

// Horizontal 3-sums from 6 inputs (halo scalars already masked by caller).
__device__ __forceinline__ void hsum6(float xl, float4 xv, float xr6,
                                      float yl, float4 yv, float yr6, HS& h)
{
    float xs[6] = { xl, xv.x, xv.y, xv.z, xv.w, xr6 };
    float ys[6] = { yl, yv.x, yv.y, yv.z, yv.w, yr6 };

    float pxx[6], pyy[6], pxy[6];
#pragma unroll
    for (int k = 0; k < 6; ++k) {
        pxx[k] = xs[k] * xs[k];
        pyy[k] = ys[k] * ys[k];
        pxy[k] = xs[k] * ys[k];
    }
#pragma unroll
    for (int j = 0; j < 4; ++j) {
        h.x[j]  = xs[j]  + xs[j + 1]  + xs[j + 2];
        h.y[j]  = ys[j]  + ys[j + 1]  + ys[j + 2];
        h.xx[j] = pxx[j] + pxx[j + 1] + pxx[j + 2];
        h.yy[j] = pyy[j] + pyy[j + 1] + pyy[j + 2];
        h.xy[j] = pxy[j] + pxy[j + 1] + pxy[j + 2];
    }
}

// Scaled SSIM (both num/den factors x81, EPS x6561; absmax==0 since R2):
//   num = (2*sx*sy + 81*C1) * (18*sxy - 2*sx*sy + 81*C2)
//   den = (sx^2+sy^2 + 81*C1) * (9*(sxx+syy) - (sx^2+sy^2) + 81*C2) + 6561*EPS
__device__ __forceinline__ void accum(const HS& A, const HS& B, const HS& C, float& acc)
{
    const float c1s  = 81.0f * 1e-4f;
    const float c2s  = 81.0f * 9e-4f;
    const float epss = 6561.0f * 1e-8f;
#pragma unroll
    for (int j = 0; j < 4; ++j) {
        const float sx  = A.x[j]  + B.x[j]  + C.x[j];
        const float sy  = A.y[j]  + B.y[j]  + C.y[j];
        const float sxx = A.xx[j] + B.xx[j] + C.xx[j];
        const float syy = A.yy[j] + B.yy[j] + C.yy[j];
        const float sxy = A.xy[j] + B.xy[j] + C.xy[j];

        const float t1 = sx * sy;
        const float t2 = fmaf(sx, sx, sy * sy);
        const float s2 = sxx + syy;
        const float An = fmaf(2.0f, t1, c1s);
        const float Bn = fmaf(-2.0f, t1, fmaf(18.0f, sxy, c2s));
        const float Xd = t2 + c1s;
        const float Yd = fmaf(9.0f, s2, c2s - t2);
        const float den = fmaf(Xd, Yd, epss);
        const float num = An * Bn;
        acc = fmaf(num, __builtin_amdgcn_rcpf(den), acc);
    }
}

// R12: register-prefetch is canonicalized away by the compiler (R8/R11 nulls,
// VGPR pinned at 56) -> switch to global_load_lds DMA, which holds NO VGPRs for
// in-flight data and uses explicit counted vmcnt (the T3/T4 discipline the
// compiler can't undo). 4-slot LDS ring (32 KB), 2 DMA/row/wave (vs 6 VMEM/row
// before), 2-row issue lead, s_waitcnt vmcnt(4) + RAW s_barrier per step (no
// __syncthreads drain). Halos come from LDS via neighbor-float4 ds_read_b128
// (conflict-free stride-16) -- the 4 scalar global gathers/row are gone.
// Ring safety: STAGE(j+2) overwrites row j-2's slot, consumed >=1 barrier ago;
// wait-then-barrier makes every wave's row-j segment visible before any read.
__global__ __launch_bounds__(TPB, 4)
void ssim_map_sum_kernel(const float* __restrict__ x,
                         const float* __restrict__ y,
                         float* __restrict__ part)
{
    __shared__ float sbuf[4][2][IMG_W];   // 4-slot ring x {x,y} row = 32 KB

    const int rb = blockIdx.x;
    const int n  = blockIdx.y;
    const int r0 = rb * RPB;
    const int t  = (int)threadIdx.x;
    const int wv = t >> 6;               // wave id: stages cols [wv*256, wv*256+256)
    const int ln = t & 63;
    const int c  = t * 4;

    const float lm = (c > 0) ? 1.0f : 0.0f;
    const float rm = (c + 4 < IMG_W) ? 1.0f : 0.0f;
    const int   tl = (t > 0) ? t - 1 : 0;            // left-neighbor float4 index
    const int   tr = (t < TPB - 1) ? t + 1 : TPB - 1; // right-neighbor float4 index

    const float* xi = x + (size_t)n * IMG_H * IMG_W;
    const float* yi = y + (size_t)n * IMG_H * IMG_W;

    // Stage input row for pipeline index j (row r0-1+j, clamped) into slot j&3.
    // Per wave: 2 DMA x 64 lanes x 16 B = its 1 KB segment of each image row.
    // LDS dest is wave-uniform base + lane*16 (HW rule); global src is per-lane.
#define STAGE(j)                                                                  \
    {                                                                             \
        const int rr_ = (r0 - 1 + (j) < 0) ? 0                                    \
                      : ((r0 - 1 + (j) > IMG_H - 1) ? IMG_H - 1 : r0 - 1 + (j));  \
        const size_t go_ = (size_t)rr_ * IMG_W + (size_t)(wv * 256 + ln * 4);     \
        __builtin_amdgcn_global_load_lds(                                         \
            (const __attribute__((address_space(1))) void*)(xi + go_),            \
            (__attribute__((address_space(3))) void*)&sbuf[(j) & 3][0][wv * 256], \
            16, 0, 0);                                                            \
        __builtin_amdgcn_global_load_lds(                                         \
            (const __attribute__((address_space(1))) void*)(yi + go_),            \
            (__attribute__((address_space(3))) void*)&sbuf[(j) & 3][1][wv * 256], \
            16, 0, 0);                                                            \
    }

    // Consume staged row j into H, inputs scaled by S (1.0 folds away; S=rwm
    // zeroes the whole clamped bottom row). Same float values as the old
    // global gathers -> bit-identical results.
#define CONSUME(j, H, S)                                                          \
    {                                                                             \
        const float4* bx_ = reinterpret_cast<const float4*>(&sbuf[(j) & 3][0][0]);\
        const float4* by_ = reinterpret_cast<const float4*>(&sbuf[(j) & 3][1][0]);\
        float4 xo_ = bx_[t], yo_ = by_[t];                                        \
        float4 xn_ = bx_[tl], yn_ = by_[tl];                                      \
        float4 xp_ = bx_[tr], yp_ = by_[tr];                                      \
        const float s_ = (S);                                                     \
        xo_.x *= s_; xo_.y *= s_; xo_.z *= s_; xo_.w *= s_;                       \
        yo_.x *= s_; yo_.y *= s_; yo_.z *= s_; yo_.w *= s_;                       \
        hsum6(xn_.w * (lm * s_), xo_, xp_.x * (rm * s_),                          \
              yn_.w * (lm * s_), yo_, yp_.x * (rm * s_), H);                      \
    }

#define WAITV(N) asm volatile("s_waitcnt vmcnt(" #N ")" ::: "memory")
#define BAR()    __builtin_amdgcn_s_barrier()

    STAGE(0)            // rows r0-1(clamped), r0 in flight before the loop
    STAGE(1)

    HS hA, hB, hC;
    float acc = 0.0f;

    // Step j consumes input row r0-1+j. Issue row j+2 FIRST (2-row DMA lead),
    // then counted wait: vmcnt(4) leaves the 2 newest row-pairs (j+1, j+2) in
    // flight and guarantees row j landed; barrier publishes all segments.
    // Tail: step 8 has no stage -> vmcnt(2); step 9 -> vmcnt(0).
    /* j=0 */ STAGE(2) WAITV(4); BAR(); CONSUME(0, hA, 1.0f)
              if (r0 == 0) zero_hs(hA);     // top edge: row r0-1 contributes 0
    /* j=1 */ STAGE(3) WAITV(4); BAR(); CONSUME(1, hB, 1.0f)
    /* j=2 */ STAGE(4) WAITV(4); BAR(); CONSUME(2, hC, 1.0f) accum(hA, hB, hC, acc);
    /* j=3 */ STAGE(5) WAITV(4); BAR(); CONSUME(3, hA, 1.0f) accum(hB, hC, hA, acc);
    /* j=4 */ STAGE(6) WAITV(4); BAR(); CONSUME(4, hB, 1.0f) accum(hC, hA, hB, acc);
    /* j=5 */ STAGE(7) WAITV(4); BAR(); CONSUME(5, hC, 1.0f) accum(hA, hB, hC, acc);
    /* j=6 */ STAGE(8) WAITV(4); BAR(); CONSUME(6, hA, 1.0f) accum(hB, hC, hA, acc);
    /* j=7 */ STAGE(9) WAITV(4); BAR(); CONSUME(7, hB, 1.0f) accum(hC, hA, hB, acc);
    /* j=8 */          WAITV(2); BAR(); CONSUME(8, hC, 1.0f) accum(hA, hB, hC, acc);
    /* j=9 */ {
        const float rwm = (r0 + 8 < IMG_H) ? 1.0f : 0.0f;   // bottom edge mask
                   WAITV(0); BAR(); CONSUME(9, hA, rwm)     accum(hB, hC, hA, acc);
    }
#undef STAGE
#undef CONSUME
#undef WAITV
#undef BAR

    // ---- Reduction: wave shuffle -> LDS (reuse slot 0; all consumes are done
    // and fenced by __syncthreads) -> ONE STORE per block.
#pragma unroll
    for (int off = 32; off > 0; off >>= 1)
        acc += __shfl_down(acc, off);

    __syncthreads();
    float* red = &sbuf[0][0][0];
    if (ln == 0) red[wv] = acc;
    __syncthreads();
    if (t == 0)
        part[blockIdx.y * gridDim.x + blockIdx.x] = red[0] + red[1] + red[2] + red[3];
}

__global__ __launch_bounds__(256)
void ssim_finalize_kernel(const float* __restrict__ part, int nparts,
                          float* __restrict__ out, float inv_count)
{
    float s = 0.0f;
    for (int i = (int)threadIdx.x; i < nparts; i += 256)
        s += part[i];
#pragma unroll
    for (int off = 32; off > 0; off >>= 1)
        s += __shfl_down(s, off);

    __shared__ float red[4];
    const int lane = (int)threadIdx.x & 63;
    const int wave = (int)threadIdx.x >> 6;
    if (lane == 0) red[wave] = s;
    __syncthreads();
    if (threadIdx.x == 0) {
        float t = red[0] + red[1] + red[2] + red[3];
        out[0] = 1.0f - t * inv_count;
    }
}

extern "C" void kernel_launch(void* const* d_in, const int* in_sizes, int n_in,
                              void* d_out, int out_size, void* d_ws, size_t ws_size,
                              hipStream_t stream)
{
    const float* x = (const float*)d_in[0];
    const float* y = (const float*)d_in[1];
    float* out  = (float*)d_out;
    float* part = (float*)d_ws;   // 4096 floats = 16 KB << ws_size

    const long long total = (long long)in_sizes[0];       // 32*1024*1024
    const int N = (int)(total / ((long long)IMG_H * IMG_W));
    const int nparts = (IMG_H / RPB) * N;

    dim3 grid(IMG_H / RPB, N);
    ssim_map_sum_kernel<<<grid, TPB, 0, stream>>>(x, y, part);

    ssim_finalize_kernel<<<1, 256, 0, stream>>>(part, nparts, out, 1.0f / (float)total);
}